// Round 16
// baseline (196.302 us; speedup 1.0000x reference)
//
#include <hip/hip_runtime.h>
#include <hip/hip_bf16.h>

#define D 512
#define T_ETYPES 8
#define NT_TYPES 4
#define K_MAIN 4096   // T_ETYPES * D
#define K_A 4608      // A row stride: 4096 msg cols + 512 root cols (type-specific)
#define K_B 6144      // WbT row stride: 4096 rel + 4*512 root windows
#define BK 64         // K-tile per barrier

// Swizzle: within each aligned 64-col (128B) tile of a row, the 16B chunk with
// logical index j (0..7) is stored at position j ^ (row & 7). Producers write
// swizzled; global_load_lds copies linearly; GEMM fragment read applies the XOR.
// SPLITS is runtime (8 if workspace fits, else 6) to pack the GEMM grid into
// full 3-blocks/CU scheduling waves (984 blocks = 1.28 waves -> 1312 = 1.71).

typedef __attribute__((ext_vector_type(8))) short bf16x8;
typedef __attribute__((ext_vector_type(4))) float f32x4;
typedef __attribute__((ext_vector_type(4))) unsigned u32x4;

__device__ __forceinline__ unsigned short f2bf(float f) {
    union { float f; unsigned u; } u{f};
    unsigned r = u.u + 0x7FFF + ((u.u >> 16) & 1);   // RNE
    return (unsigned short)(r >> 16);
}
__device__ __forceinline__ float bf2f(unsigned short h) {
    union { unsigned u; float f; } v{(unsigned)h << 16};
    return v.f;
}

__device__ __forceinline__ void gl16(const unsigned short* g, unsigned short* l) {
    __builtin_amdgcn_global_load_lds(
        (const __attribute__((address_space(1))) unsigned int*)g,
        (__attribute__((address_space(3))) unsigned int*)l,
        16, 0, 0);
}

// ---- FRONT: convert_xsrc || convert_weights || hist || thist2 (all independent)
__global__ void front_kernel(const float* __restrict__ x, unsigned short* __restrict__ xb,
                             int n8,
                             const float* __restrict__ relW, const float* __restrict__ rootW,
                             unsigned short* __restrict__ WbT,
                             const int* __restrict__ edst, const int* __restrict__ etyp,
                             int* __restrict__ counts, int E,
                             const int* __restrict__ tnt, int* __restrict__ bcnt, int M,
                             int convBlocks, int cwBlocks, int histBlocks) {
    int b = blockIdx.x;
    if (b < convBlocks) {
        int stride = convBlocks * 256;
        for (int i = b * 256 + threadIdx.x; i < n8; i += stride) {
            const float4* p = reinterpret_cast<const float4*>(x + (size_t)i * 8);
            float4 v0 = p[0], v1 = p[1];
            uint4 u;
            u.x = (unsigned)f2bf(v0.x) | ((unsigned)f2bf(v0.y) << 16);
            u.y = (unsigned)f2bf(v0.z) | ((unsigned)f2bf(v0.w) << 16);
            u.z = (unsigned)f2bf(v1.x) | ((unsigned)f2bf(v1.y) << 16);
            u.w = (unsigned)f2bf(v1.z) | ((unsigned)f2bf(v1.w) << 16);
            reinterpret_cast<uint4*>(xb)[i] = u;
        }
        return;
    }
    b -= convBlocks;
    if (b < cwBlocks) {
        __shared__ float tile[32][33];
        int c0 = (b % (K_B / 32)) * 32;
        int o0 = (b / (K_B / 32)) * 32;
        int tid = threadIdx.x;
#pragma unroll
        for (int it = 0; it < 4; ++it) {
            int idx = it * 256 + tid;
            int oc = idx & 31, cc = idx >> 5;
            int c = c0 + cc, o = o0 + oc;
            float v = (c < K_MAIN) ? relW[(size_t)c * D + o]
                                   : rootW[(size_t)(c - K_MAIN) * D + o];
            tile[cc][oc] = v;
        }
        __syncthreads();
#pragma unroll
        for (int it = 0; it < 4; ++it) {
            int idx = it * 256 + tid;
            int cc = idx & 31, oc = idx >> 5;
            int o = o0 + oc, c = c0 + cc;
            int csw = (c & ~63) | (((((c >> 3) & 7) ^ (o & 7))) << 3) | (c & 7);
            WbT[(size_t)o * K_B + csw] = f2bf(tile[cc][oc]);
        }
        return;
    }
    b -= cwBlocks;
    if (b < histBlocks) {
        int e = b * 256 + threadIdx.x;
        if (e < E) atomicAdd(&counts[edst[e] * T_ETYPES + etyp[e]], 1);
        return;
    }
    b -= histBlocks;
    {
        __shared__ int h[NT_TYPES];
        if (threadIdx.x < NT_TYPES) h[threadIdx.x] = 0;
        __syncthreads();
        int i = b * 256 + threadIdx.x;
        if (i < M) atomicAdd(&h[tnt[i]], 1);
        __syncthreads();
        if (threadIdx.x < NT_TYPES) bcnt[b * NT_TYPES + threadIdx.x] = h[threadIdx.x];
    }
}

// ---- MID1: scan1 (blocks [0,NB)) || tprep2 (block NB)
__global__ void mid1(const int* __restrict__ counts, int* __restrict__ partial,
                     int* __restrict__ blockSums, int n,
                     const int* __restrict__ bcnt, int nbt, int* __restrict__ boff,
                     int* __restrict__ gstart, int* __restrict__ endv, int NBscan) {
    if ((int)blockIdx.x < NBscan) {
        __shared__ int sh[256];
        int tid = threadIdx.x, i = blockIdx.x * 256 + tid;
        int c = (i < n) ? counts[i] : 0;
        int val = c;
        sh[tid] = val; __syncthreads();
#pragma unroll
        for (int off = 1; off < 256; off <<= 1) {
            int add = (tid >= off) ? sh[tid - off] : 0;
            __syncthreads();
            val += add; sh[tid] = val;
            __syncthreads();
        }
        if (i < n) partial[i] = val - c;
        if (tid == 255) blockSums[blockIdx.x] = val;
        return;
    }
    __shared__ int sb[128 * NT_TYPES];
    __shared__ int gs[NT_TYPES];
    int tid = threadIdx.x;
    for (int i = tid; i < nbt * NT_TYPES; i += blockDim.x) sb[i] = bcnt[i];
    __syncthreads();
    if (tid == 0) {
        int s = 0;
        for (int g = 0; g < NT_TYPES; ++g) {
            int tot = 0;
            for (int b2 = 0; b2 < nbt; ++b2) tot += sb[b2 * NT_TYPES + g];
            gs[g] = s;
            gstart[g] = s;
            endv[g] = s + tot;
            s += ((tot + 127) >> 7) << 7;
        }
        gstart[NT_TYPES] = s;
    }
    __syncthreads();
    if (tid < NT_TYPES) {
        int run = gs[tid];
        for (int b2 = 0; b2 < nbt; ++b2) {
            boff[b2 * NT_TYPES + tid] = run;
            run += sb[b2 * NT_TYPES + tid];
        }
    }
}

// ---- MID2 (512 threads): scan2 (block 0) || tscatter2 (blocks 1..)
__global__ void mid2(int* __restrict__ blockSums, int nb,
                     const int* __restrict__ tnt, const int* __restrict__ boff,
                     int* __restrict__ rowperm, int* __restrict__ invperm,
                     int M, int nbt) {
    if (blockIdx.x == 0) {
        __shared__ int sh[512];
        int tid = threadIdx.x;
        int c = (tid < nb) ? blockSums[tid] : 0;
        int val = c;
        sh[tid] = val; __syncthreads();
#pragma unroll
        for (int off = 1; off < 512; off <<= 1) {
            int add = (tid >= off) ? sh[tid - off] : 0;
            __syncthreads();
            val += add; sh[tid] = val;
            __syncthreads();
        }
        if (tid < nb) blockSums[tid] = val - c;
        return;
    }
    __shared__ int h[2][NT_TYPES];
    int half = threadIdx.x >> 8;
    int tid = threadIdx.x & 255;
    int lb = ((int)blockIdx.x - 1) * 2 + half;
    if (tid < NT_TYPES) h[half][tid] = 0;
    __syncthreads();
    int n = lb * 256 + tid;
    if (lb < nbt && n < M) {
        int g = tnt[n];
        int lr = atomicAdd(&h[half][g], 1);
        int p = boff[lb * NT_TYPES + g] + lr;
        rowperm[p] = n;
        invperm[n] = p;
    }
}

__global__ void scan3(const int* __restrict__ partial, const int* __restrict__ blockSums,
                      int* __restrict__ offsets, int* __restrict__ cursors, int n, int E) {
    int i = blockIdx.x * 256 + threadIdx.x;
    if (i < n) {
        int v = partial[i] + blockSums[i >> 8];
        offsets[i] = v;
        cursors[i] = v;
    }
    if (i == 0) offsets[n] = E;
}

__global__ void scatter_kernel(const int* __restrict__ esrc, const int* __restrict__ edst,
                               const int* __restrict__ etyp, int* __restrict__ cursors,
                               int* __restrict__ perm, int E) {
    int e = blockIdx.x * 256 + threadIdx.x;
    if (e < E) {
        int seg = edst[e] * T_ETYPES + etyp[e];
        int pos = atomicAdd(&cursors[seg], 1);
        perm[pos] = esrc[e];
    }
}

// ---- fused: segment mean over bf16 x_src (4-wide speculative blocks) + root fill
__global__ void build_A(const unsigned short* __restrict__ xsb, const int* __restrict__ perm,
                        const int* __restrict__ offsets,
                        const int* __restrict__ invperm, const float* __restrict__ x_target,
                        unsigned short* __restrict__ A, int nseg, int segBlocks, int M) {
    if ((int)blockIdx.x >= segBlocks) {
        int idx = ((int)blockIdx.x - segBlocks) * 256 + threadIdx.x;
        if (idx >= M * 64) return;
        int n = idx >> 6;
        int q = idx & 63;
        const float4* p = reinterpret_cast<const float4*>(x_target + (size_t)n * D + q * 8);
        float4 v0 = p[0], v1 = p[1];
        uint4 u;
        u.x = (unsigned)f2bf(v0.x) | ((unsigned)f2bf(v0.y) << 16);
        u.y = (unsigned)f2bf(v0.z) | ((unsigned)f2bf(v0.w) << 16);
        u.z = (unsigned)f2bf(v1.x) | ((unsigned)f2bf(v1.y) << 16);
        u.w = (unsigned)f2bf(v1.z) | ((unsigned)f2bf(v1.w) << 16);
        int prow = invperm[n];
        int col = K_MAIN + ((q >> 3) << 6) + (((q & 7) ^ (prow & 7)) << 3);
        *reinterpret_cast<uint4*>(A + (size_t)prow * K_A + col) = u;
        return;
    }
    int seg = blockIdx.x * 4 + (threadIdx.x >> 6);
    if (seg >= nseg) return;
    int lane = threadIdx.x & 63;
    int beg = offsets[seg];
    int cnt = offsets[seg + 1] - beg;

    float4 a0 = make_float4(0.f, 0.f, 0.f, 0.f);
    float4 a1 = make_float4(0.f, 0.f, 0.f, 0.f);

#define ACCUM(R) {                                                                  \
        a0.x += bf2f((unsigned short)R.x); a0.y += bf2f((unsigned short)(R.x >> 16));\
        a0.z += bf2f((unsigned short)R.y); a0.w += bf2f((unsigned short)(R.y >> 16));\
        a1.x += bf2f((unsigned short)R.z); a1.y += bf2f((unsigned short)(R.z >> 16));\
        a1.z += bf2f((unsigned short)R.w); a1.w += bf2f((unsigned short)(R.w >> 16));}

    for (int i = 0; i < cnt; i += 4) {
        int last = beg + cnt - 1;
        int c0 = beg + i;
        int c1 = min(beg + i + 1, last);
        int c2 = min(beg + i + 2, last);
        int c3 = min(beg + i + 3, last);
        int s0 = perm[c0], s1 = perm[c1], s2 = perm[c2], s3 = perm[c3];
        uint4 r0 = reinterpret_cast<const uint4*>(xsb + (size_t)s0 * D)[lane];
        uint4 r1 = reinterpret_cast<const uint4*>(xsb + (size_t)s1 * D)[lane];
        uint4 r2 = reinterpret_cast<const uint4*>(xsb + (size_t)s2 * D)[lane];
        uint4 r3 = reinterpret_cast<const uint4*>(xsb + (size_t)s3 * D)[lane];
        ACCUM(r0)
        if (i + 1 < cnt) ACCUM(r1)
        if (i + 2 < cnt) ACCUM(r2)
        if (i + 3 < cnt) ACCUM(r3)
    }
#undef ACCUM

    float sc = (cnt > 0) ? 1.0f / (float)cnt : 0.0f;
    uint4 u;
    u.x = (unsigned)f2bf(a0.x * sc) | ((unsigned)f2bf(a0.y * sc) << 16);
    u.y = (unsigned)f2bf(a0.z * sc) | ((unsigned)f2bf(a0.w * sc) << 16);
    u.z = (unsigned)f2bf(a1.x * sc) | ((unsigned)f2bf(a1.y * sc) << 16);
    u.w = (unsigned)f2bf(a1.z * sc) | ((unsigned)f2bf(a1.w * sc) << 16);
    int dst = seg >> 3, t = seg & 7;
    int nrow = invperm[dst];
    int col = t * D + ((lane >> 3) << 6) + (((lane & 7) ^ (nrow & 7)) << 3);
    *reinterpret_cast<uint4*>(A + (size_t)nrow * K_A + col) = u;
}

// ---- split-K GEMM, 128x256 tile, 512 threads (8 waves), BK=64, swizzle-read
// ksplit is runtime (576 for SPLITS=8, 768 for SPLITS=6); all K-tile boundaries
// are multiples of 64 so the per-tile K_MAIN crossover check is unchanged.
__global__ __launch_bounds__(512, 4)
void rgcn_gemm_sk(const unsigned short* __restrict__ A,
                  const unsigned short* __restrict__ WbT,
                  unsigned short* __restrict__ pbuf,
                  const int* __restrict__ gstart, const int* __restrict__ endv,
                  int MBP, int MPc, int ksplit) {
    __shared__ unsigned short As[128 * BK];   // 16 KB
    __shared__ unsigned short Bs[256 * BK];   // 32 KB
    const int tid = threadIdx.x;

    int d = blockIdx.x;
    int l = d;
    if ((gridDim.x & 7) == 0) {
        int cpx = gridDim.x >> 3;
        l = (d & 7) * cpx + (d >> 3);
    }
    const int nIdx = l & 1;
    const int mz = l >> 1;
    const int mIdx = mz % MBP;
    const int zIdx = mz / MBP;

    const int blockM = mIdx * 128;
    const int blockN = nIdx * 256;
    const int kBase = zIdx * ksplit;
    const int g = (blockM >= gstart[1]) + (blockM >= gstart[2]) + (blockM >= gstart[3]);
    const int endRow = endv[g];
    const int rootOff = g * 512;

    const int wid = tid >> 6, lane = tid & 63;
    const int wr = wid >> 2, wc = wid & 3;     // 2 x 4 wave grid, 64x64 out each
    const int lr = lane & 15, lg = lane >> 4;

    f32x4 acc[4][4] = {};

    const unsigned short* Abase = A + (size_t)blockM * K_A + kBase;
    const unsigned short* Bbase = WbT + (size_t)blockN * K_B;

    const int ntiles = ksplit / BK;
    for (int t = 0; t < ntiles; ++t) {
        const int k0 = t * BK;
        const int kc = kBase + k0;
        const int bc = (kc < K_MAIN) ? kc : kc + rootOff;   // uniform per 64-tile
#pragma unroll
        for (int q = 0; q < 2; ++q) {
            int c = q * 512 + tid;
            gl16(Abase + (size_t)(c >> 3) * K_A + k0 + (c & 7) * 8, &As[c * 8]);
        }
#pragma unroll
        for (int q = 0; q < 4; ++q) {
            int c = q * 512 + tid;
            gl16(Bbase + (size_t)(c >> 3) * K_B + bc + (c & 7) * 8, &Bs[c * 8]);
        }
        __syncthreads();

#pragma unroll
        for (int ks = 0; ks < 2; ++ks) {
            bf16x8 a_frag[4], b_frag[4];
#pragma unroll
            for (int mi = 0; mi < 4; ++mi) {
                int r = wr * 64 + mi * 16 + lr;
                a_frag[mi] = *reinterpret_cast<const bf16x8*>(
                    &As[r * BK + (((ks * 4 + lg) ^ (r & 7)) << 3)]);
            }
#pragma unroll
            for (int ni = 0; ni < 4; ++ni) {
                int cR = wc * 64 + ni * 16 + lr;
                b_frag[ni] = *reinterpret_cast<const bf16x8*>(
                    &Bs[cR * BK + (((ks * 4 + lg) ^ (cR & 7)) << 3)]);
            }
#pragma unroll
            for (int mi = 0; mi < 4; ++mi)
#pragma unroll
                for (int ni = 0; ni < 4; ++ni)
                    acc[mi][ni] = __builtin_amdgcn_mfma_f32_16x16x32_bf16(
                        a_frag[mi], b_frag[ni], acc[mi][ni], 0, 0, 0);
        }
        __syncthreads();
    }

#pragma unroll
    for (int mi = 0; mi < 4; ++mi) {
#pragma unroll
        for (int r = 0; r < 4; ++r) {
            int row = blockM + wr * 64 + mi * 16 + lg * 4 + r;
            if (row < endRow) {
#pragma unroll
                for (int ni = 0; ni < 4; ++ni) {
                    int col = blockN + wc * 64 + ni * 16 + lr;
                    __builtin_nontemporal_store(f2bf(acc[mi][ni][r]),
                        &pbuf[((size_t)zIdx * MPc + row) * D + col]);
                }
            }
        }
    }
}

// ---- reduce splits + per-type bias -> f32 out (un-permute rows, NT load/store)
__global__ void reduce_bias(const unsigned short* __restrict__ pbuf,
                            const int* __restrict__ rowperm, const int* __restrict__ tnt,
                            const float* __restrict__ root_b,
                            float* __restrict__ out, int MPc, int splits) {
    int idx = blockIdx.x * 256 + threadIdx.x;
    if (idx >= MPc * 64) return;
    int nrow = idx >> 6;
    int col = (idx & 63) * 8;
    int orig = rowperm[nrow];
    if (orig < 0) return;
    float s[8] = {0.f, 0.f, 0.f, 0.f, 0.f, 0.f, 0.f, 0.f};
    for (int sp = 0; sp < splits; ++sp) {
        u32x4 v = __builtin_nontemporal_load(
            reinterpret_cast<const u32x4*>(pbuf + ((size_t)sp * MPc + nrow) * D + col));
        unsigned u[4] = {v.x, v.y, v.z, v.w};
#pragma unroll
        for (int j = 0; j < 4; ++j) {
            s[2 * j]     += bf2f((unsigned short)(u[j] & 0xFFFF));
            s[2 * j + 1] += bf2f((unsigned short)(u[j] >> 16));
        }
    }
    const float* b = root_b + (size_t)tnt[orig] * D + col;
    float* o = out + (size_t)orig * D + col;
#pragma unroll
    for (int j = 0; j < 8; ++j)
        __builtin_nontemporal_store(s[j] + b[j], o + j);
}

extern "C" void kernel_launch(void* const* d_in, const int* in_sizes, int n_in,
                              void* d_out, int out_size, void* d_ws, size_t ws_size,
                              hipStream_t stream) {
    const float* x_src    = (const float*)d_in[0];
    const float* x_target = (const float*)d_in[1];
    const float* relW     = (const float*)d_in[2];
    const float* rootW    = (const float*)d_in[3];
    const float* rootb    = (const float*)d_in[4];
    const int*   esrc     = (const int*)d_in[5];
    const int*   edst     = (const int*)d_in[6];
    const int*   etyp     = (const int*)d_in[7];
    const int*   tnt      = (const int*)d_in[8];
    float* out = (float*)d_out;

    const int E = in_sizes[5];
    const int NSRC8 = in_sizes[0] / 8;
    const int M = in_sizes[8];               // n_tgt = 10000
    const int NSEG = M * T_ETYPES;           // 80000
    const int NB = (NSEG + 255) / 256;       // 313
    const int NBT = (M + 255) / 256;         // 40
    const int MBP = (M + 127) / 128 + (NT_TYPES - 1);  // 82
    const int MPc = MBP * 128;               // 10496
    const int segBlocks = (NSEG + 3) / 4;    // 20000
    const int rootBlocks = (M * 64 + 255) / 256;
    const int convBlocks = 2048;
    const int cwBlocks = (K_B / 32) * (D / 32);
    const int histBlocks = (E + 255) / 256;

    // ---- choose SPLITS: 8 (grid 1312 = 1.71 waves of 768) if ws fits, else 6.
    size_t fixed_bytes = (size_t)MPc * K_A * 2 + (size_t)D * K_B * 2;
    size_t xsb_bytes = (size_t)in_sizes[0] * 2;
    size_t tail_bytes = (size_t)NSEG * 4 * 3 + (size_t)(NSEG + 8) * 4 + 512 * 4 +
                        (size_t)E * 4 + (size_t)NBT * NT_TYPES * 8 + 64 * 4 +
                        (size_t)MPc * 4 + (size_t)M * 4 + 1024;
    int splits = 8;
    {
        size_t pbb = (size_t)splits * MPc * D * 2;
        size_t alias = pbb > xsb_bytes ? pbb : xsb_bytes;
        if (fixed_bytes + alias + tail_bytes > ws_size) splits = 6;
    }
    const int ksplit = K_A / splits;         // 576 or 768 (both multiples of 64)

    char* ws = (char*)d_ws;
    size_t off = 0;
    unsigned short* Abf = (unsigned short*)(ws + off); off += (size_t)MPc * K_A * 2;
    unsigned short* WbT = (unsigned short*)(ws + off); off += (size_t)D * K_B * 2;
    size_t pb_bytes = (size_t)splits * MPc * D * 2;
    size_t alias_bytes = pb_bytes > xsb_bytes ? pb_bytes : xsb_bytes;
    unsigned short* xsb = (unsigned short*)(ws + off);
    unsigned short* pb  = (unsigned short*)(ws + off);
    off += alias_bytes;
    int* counts    = (int*)(ws + off); off += (size_t)NSEG * 4;
    int* partial   = (int*)(ws + off); off += (size_t)NSEG * 4;
    int* offsets   = (int*)(ws + off); off += (size_t)(NSEG + 8) * 4;
    int* cursors   = (int*)(ws + off); off += (size_t)NSEG * 4;
    int* blockSums = (int*)(ws + off); off += 512 * 4;
    int* perm      = (int*)(ws + off); off += (size_t)E * 4;
    int* bcnt      = (int*)(ws + off); off += (size_t)NBT * NT_TYPES * 4;
    int* boff      = (int*)(ws + off); off += (size_t)NBT * NT_TYPES * 4;
    int* gstart    = (int*)(ws + off); off += 8 * 4;
    int* endv      = (int*)(ws + off); off += 8 * 4;
    int* rowperm   = (int*)(ws + off); off += (size_t)MPc * 4;
    int* invperm   = (int*)(ws + off); off += (size_t)M * 4;

    hipMemsetAsync(counts, 0, (size_t)NSEG * 4, stream);
    hipMemsetAsync(rowperm, 0xFF, (size_t)MPc * 4, stream);

    // fused front: conv_xsrc || conv_weights || hist || thist2
    front_kernel<<<convBlocks + cwBlocks + histBlocks + NBT, 256, 0, stream>>>(
        x_src, xsb, NSRC8, relW, rootW, WbT, edst, etyp, counts, E,
        tnt, bcnt, M, convBlocks, cwBlocks, histBlocks);
    // fused: scan1 || tprep2
    mid1<<<NB + 1, 256, 0, stream>>>(counts, partial, blockSums, NSEG,
                                     bcnt, NBT, boff, gstart, endv, NB);
    // fused: scan2 || tscatter2
    mid2<<<1 + (NBT + 1) / 2, 512, 0, stream>>>(blockSums, NB, tnt, boff,
                                                rowperm, invperm, M, NBT);
    scan3<<<NB, 256, 0, stream>>>(partial, blockSums, offsets, cursors, NSEG, E);
    scatter_kernel<<<histBlocks, 256, 0, stream>>>(esrc, edst, etyp, cursors, perm, E);
    // build A (bf16 gather + fused rootfill, swizzled)
    build_A<<<segBlocks + rootBlocks, 256, 0, stream>>>(
        xsb, perm, offsets, invperm, x_target, Abf, NSEG, segBlocks, M);
    // GEMM (128x256 tile, 512 threads) + reduce
    rgcn_gemm_sk<<<MBP * 2 * splits, 512, 0, stream>>>(Abf, WbT, pb, gstart, endv,
                                                       MBP, MPc, ksplit);
    reduce_bias<<<(MPc * 64 + 255) / 256, 256, 0, stream>>>(pb, rowperm, tnt, rootb,
                                                            out, MPc, splits);
}

// Round 17
// 180.570 us; speedup vs baseline: 1.0871x; 1.0871x over previous
//
#include <hip/hip_runtime.h>
#include <hip/hip_bf16.h>

#define D 512
#define T_ETYPES 8
#define NT_TYPES 4
#define K_MAIN 4096   // T_ETYPES * D
#define K_A 4608      // A row stride: 4096 msg cols + 512 root cols (type-specific)
#define K_B 6144      // WbT row stride: 4096 rel + 4*512 root windows
#define SPLITS 6
#define KSPLIT 768    // K_A / SPLITS (12 tiles of 64)
#define BK 64         // K-tile per barrier

// Swizzle: within each aligned 64-col (128B) tile of a row, the 16B chunk with
// logical index j (0..7) is stored at position j ^ (row & 7). Producers write
// swizzled; global_load_lds copies linearly; GEMM fragment read applies the XOR.
// SPLITS=6 is the measured optimum (8 regressed via +33% partial traffic).
// pbuf uses NORMAL stores/loads (L2-serviced write-then-read); NT only on out.

typedef __attribute__((ext_vector_type(8))) short bf16x8;
typedef __attribute__((ext_vector_type(4))) float f32x4;

__device__ __forceinline__ unsigned short f2bf(float f) {
    union { float f; unsigned u; } u{f};
    unsigned r = u.u + 0x7FFF + ((u.u >> 16) & 1);   // RNE
    return (unsigned short)(r >> 16);
}
__device__ __forceinline__ float bf2f(unsigned short h) {
    union { unsigned u; float f; } v{(unsigned)h << 16};
    return v.f;
}

__device__ __forceinline__ void gl16(const unsigned short* g, unsigned short* l) {
    __builtin_amdgcn_global_load_lds(
        (const __attribute__((address_space(1))) unsigned int*)g,
        (__attribute__((address_space(3))) unsigned int*)l,
        16, 0, 0);
}

// ---- FRONT: convert_xsrc || convert_weights || hist || thist2 (all independent)
__global__ void front_kernel(const float* __restrict__ x, unsigned short* __restrict__ xb,
                             int n8,
                             const float* __restrict__ relW, const float* __restrict__ rootW,
                             unsigned short* __restrict__ WbT,
                             const int* __restrict__ edst, const int* __restrict__ etyp,
                             int* __restrict__ counts, int E,
                             const int* __restrict__ tnt, int* __restrict__ bcnt, int M,
                             int convBlocks, int cwBlocks, int histBlocks) {
    int b = blockIdx.x;
    if (b < convBlocks) {
        int stride = convBlocks * 256;
        for (int i = b * 256 + threadIdx.x; i < n8; i += stride) {
            const float4* p = reinterpret_cast<const float4*>(x + (size_t)i * 8);
            float4 v0 = p[0], v1 = p[1];
            uint4 u;
            u.x = (unsigned)f2bf(v0.x) | ((unsigned)f2bf(v0.y) << 16);
            u.y = (unsigned)f2bf(v0.z) | ((unsigned)f2bf(v0.w) << 16);
            u.z = (unsigned)f2bf(v1.x) | ((unsigned)f2bf(v1.y) << 16);
            u.w = (unsigned)f2bf(v1.z) | ((unsigned)f2bf(v1.w) << 16);
            reinterpret_cast<uint4*>(xb)[i] = u;
        }
        return;
    }
    b -= convBlocks;
    if (b < cwBlocks) {
        __shared__ float tile[32][33];
        int c0 = (b % (K_B / 32)) * 32;
        int o0 = (b / (K_B / 32)) * 32;
        int tid = threadIdx.x;
#pragma unroll
        for (int it = 0; it < 4; ++it) {
            int idx = it * 256 + tid;
            int oc = idx & 31, cc = idx >> 5;
            int c = c0 + cc, o = o0 + oc;
            float v = (c < K_MAIN) ? relW[(size_t)c * D + o]
                                   : rootW[(size_t)(c - K_MAIN) * D + o];
            tile[cc][oc] = v;
        }
        __syncthreads();
#pragma unroll
        for (int it = 0; it < 4; ++it) {
            int idx = it * 256 + tid;
            int cc = idx & 31, oc = idx >> 5;
            int o = o0 + oc, c = c0 + cc;
            int csw = (c & ~63) | (((((c >> 3) & 7) ^ (o & 7))) << 3) | (c & 7);
            WbT[(size_t)o * K_B + csw] = f2bf(tile[cc][oc]);
        }
        return;
    }
    b -= cwBlocks;
    if (b < histBlocks) {
        int e = b * 256 + threadIdx.x;
        if (e < E) atomicAdd(&counts[edst[e] * T_ETYPES + etyp[e]], 1);
        return;
    }
    b -= histBlocks;
    {
        __shared__ int h[NT_TYPES];
        if (threadIdx.x < NT_TYPES) h[threadIdx.x] = 0;
        __syncthreads();
        int i = b * 256 + threadIdx.x;
        if (i < M) atomicAdd(&h[tnt[i]], 1);
        __syncthreads();
        if (threadIdx.x < NT_TYPES) bcnt[b * NT_TYPES + threadIdx.x] = h[threadIdx.x];
    }
}

// ---- MID1: scan1 (blocks [0,NB)) || tprep2 (block NB)
__global__ void mid1(const int* __restrict__ counts, int* __restrict__ partial,
                     int* __restrict__ blockSums, int n,
                     const int* __restrict__ bcnt, int nbt, int* __restrict__ boff,
                     int* __restrict__ gstart, int* __restrict__ endv, int NBscan) {
    if ((int)blockIdx.x < NBscan) {
        __shared__ int sh[256];
        int tid = threadIdx.x, i = blockIdx.x * 256 + tid;
        int c = (i < n) ? counts[i] : 0;
        int val = c;
        sh[tid] = val; __syncthreads();
#pragma unroll
        for (int off = 1; off < 256; off <<= 1) {
            int add = (tid >= off) ? sh[tid - off] : 0;
            __syncthreads();
            val += add; sh[tid] = val;
            __syncthreads();
        }
        if (i < n) partial[i] = val - c;
        if (tid == 255) blockSums[blockIdx.x] = val;
        return;
    }
    __shared__ int sb[128 * NT_TYPES];
    __shared__ int gs[NT_TYPES];
    int tid = threadIdx.x;
    for (int i = tid; i < nbt * NT_TYPES; i += blockDim.x) sb[i] = bcnt[i];
    __syncthreads();
    if (tid == 0) {
        int s = 0;
        for (int g = 0; g < NT_TYPES; ++g) {
            int tot = 0;
            for (int b2 = 0; b2 < nbt; ++b2) tot += sb[b2 * NT_TYPES + g];
            gs[g] = s;
            gstart[g] = s;
            endv[g] = s + tot;
            s += ((tot + 127) >> 7) << 7;
        }
        gstart[NT_TYPES] = s;
    }
    __syncthreads();
    if (tid < NT_TYPES) {
        int run = gs[tid];
        for (int b2 = 0; b2 < nbt; ++b2) {
            boff[b2 * NT_TYPES + tid] = run;
            run += sb[b2 * NT_TYPES + tid];
        }
    }
}

// ---- MID2 (512 threads): scan2 (block 0) || tscatter2 (blocks 1..)
__global__ void mid2(int* __restrict__ blockSums, int nb,
                     const int* __restrict__ tnt, const int* __restrict__ boff,
                     int* __restrict__ rowperm, int* __restrict__ invperm,
                     int M, int nbt) {
    if (blockIdx.x == 0) {
        __shared__ int sh[512];
        int tid = threadIdx.x;
        int c = (tid < nb) ? blockSums[tid] : 0;
        int val = c;
        sh[tid] = val; __syncthreads();
#pragma unroll
        for (int off = 1; off < 512; off <<= 1) {
            int add = (tid >= off) ? sh[tid - off] : 0;
            __syncthreads();
            val += add; sh[tid] = val;
            __syncthreads();
        }
        if (tid < nb) blockSums[tid] = val - c;
        return;
    }
    __shared__ int h[2][NT_TYPES];
    int half = threadIdx.x >> 8;
    int tid = threadIdx.x & 255;
    int lb = ((int)blockIdx.x - 1) * 2 + half;
    if (tid < NT_TYPES) h[half][tid] = 0;
    __syncthreads();
    int n = lb * 256 + tid;
    if (lb < nbt && n < M) {
        int g = tnt[n];
        int lr = atomicAdd(&h[half][g], 1);
        int p = boff[lb * NT_TYPES + g] + lr;
        rowperm[p] = n;
        invperm[n] = p;
    }
}

__global__ void scan3(const int* __restrict__ partial, const int* __restrict__ blockSums,
                      int* __restrict__ offsets, int* __restrict__ cursors, int n, int E) {
    int i = blockIdx.x * 256 + threadIdx.x;
    if (i < n) {
        int v = partial[i] + blockSums[i >> 8];
        offsets[i] = v;
        cursors[i] = v;
    }
    if (i == 0) offsets[n] = E;
}

__global__ void scatter_kernel(const int* __restrict__ esrc, const int* __restrict__ edst,
                               const int* __restrict__ etyp, int* __restrict__ cursors,
                               int* __restrict__ perm, int E) {
    int e = blockIdx.x * 256 + threadIdx.x;
    if (e < E) {
        int seg = edst[e] * T_ETYPES + etyp[e];
        int pos = atomicAdd(&cursors[seg], 1);
        perm[pos] = esrc[e];
    }
}

// ---- fused: segment mean over bf16 x_src (4-wide speculative blocks) + root fill
__global__ void build_A(const unsigned short* __restrict__ xsb, const int* __restrict__ perm,
                        const int* __restrict__ offsets,
                        const int* __restrict__ invperm, const float* __restrict__ x_target,
                        unsigned short* __restrict__ A, int nseg, int segBlocks, int M) {
    if ((int)blockIdx.x >= segBlocks) {
        int idx = ((int)blockIdx.x - segBlocks) * 256 + threadIdx.x;
        if (idx >= M * 64) return;
        int n = idx >> 6;
        int q = idx & 63;
        const float4* p = reinterpret_cast<const float4*>(x_target + (size_t)n * D + q * 8);
        float4 v0 = p[0], v1 = p[1];
        uint4 u;
        u.x = (unsigned)f2bf(v0.x) | ((unsigned)f2bf(v0.y) << 16);
        u.y = (unsigned)f2bf(v0.z) | ((unsigned)f2bf(v0.w) << 16);
        u.z = (unsigned)f2bf(v1.x) | ((unsigned)f2bf(v1.y) << 16);
        u.w = (unsigned)f2bf(v1.z) | ((unsigned)f2bf(v1.w) << 16);
        int prow = invperm[n];
        int col = K_MAIN + ((q >> 3) << 6) + (((q & 7) ^ (prow & 7)) << 3);
        *reinterpret_cast<uint4*>(A + (size_t)prow * K_A + col) = u;
        return;
    }
    int seg = blockIdx.x * 4 + (threadIdx.x >> 6);
    if (seg >= nseg) return;
    int lane = threadIdx.x & 63;
    int beg = offsets[seg];
    int cnt = offsets[seg + 1] - beg;

    float4 a0 = make_float4(0.f, 0.f, 0.f, 0.f);
    float4 a1 = make_float4(0.f, 0.f, 0.f, 0.f);

#define ACCUM(R) {                                                                  \
        a0.x += bf2f((unsigned short)R.x); a0.y += bf2f((unsigned short)(R.x >> 16));\
        a0.z += bf2f((unsigned short)R.y); a0.w += bf2f((unsigned short)(R.y >> 16));\
        a1.x += bf2f((unsigned short)R.z); a1.y += bf2f((unsigned short)(R.z >> 16));\
        a1.z += bf2f((unsigned short)R.w); a1.w += bf2f((unsigned short)(R.w >> 16));}

    for (int i = 0; i < cnt; i += 4) {
        int last = beg + cnt - 1;
        int c0 = beg + i;
        int c1 = min(beg + i + 1, last);
        int c2 = min(beg + i + 2, last);
        int c3 = min(beg + i + 3, last);
        int s0 = perm[c0], s1 = perm[c1], s2 = perm[c2], s3 = perm[c3];
        uint4 r0 = reinterpret_cast<const uint4*>(xsb + (size_t)s0 * D)[lane];
        uint4 r1 = reinterpret_cast<const uint4*>(xsb + (size_t)s1 * D)[lane];
        uint4 r2 = reinterpret_cast<const uint4*>(xsb + (size_t)s2 * D)[lane];
        uint4 r3 = reinterpret_cast<const uint4*>(xsb + (size_t)s3 * D)[lane];
        ACCUM(r0)
        if (i + 1 < cnt) ACCUM(r1)
        if (i + 2 < cnt) ACCUM(r2)
        if (i + 3 < cnt) ACCUM(r3)
    }
#undef ACCUM

    float sc = (cnt > 0) ? 1.0f / (float)cnt : 0.0f;
    uint4 u;
    u.x = (unsigned)f2bf(a0.x * sc) | ((unsigned)f2bf(a0.y * sc) << 16);
    u.y = (unsigned)f2bf(a0.z * sc) | ((unsigned)f2bf(a0.w * sc) << 16);
    u.z = (unsigned)f2bf(a1.x * sc) | ((unsigned)f2bf(a1.y * sc) << 16);
    u.w = (unsigned)f2bf(a1.z * sc) | ((unsigned)f2bf(a1.w * sc) << 16);
    int dst = seg >> 3, t = seg & 7;
    int nrow = invperm[dst];
    int col = t * D + ((lane >> 3) << 6) + (((lane & 7) ^ (nrow & 7)) << 3);
    *reinterpret_cast<uint4*>(A + (size_t)nrow * K_A + col) = u;
}

// ---- split-K GEMM, 128x256 tile, 512 threads (8 waves), BK=64, swizzle-read
__global__ __launch_bounds__(512, 4)
void rgcn_gemm_sk(const unsigned short* __restrict__ A,
                  const unsigned short* __restrict__ WbT,
                  unsigned short* __restrict__ pbuf,
                  const int* __restrict__ gstart, const int* __restrict__ endv,
                  int MBP, int MPc) {
    __shared__ unsigned short As[128 * BK];   // 16 KB
    __shared__ unsigned short Bs[256 * BK];   // 32 KB
    const int tid = threadIdx.x;

    int d = blockIdx.x;
    int l = d;
    if ((gridDim.x & 7) == 0) {
        int cpx = gridDim.x >> 3;
        l = (d & 7) * cpx + (d >> 3);
    }
    const int nIdx = l & 1;
    const int mz = l >> 1;
    const int mIdx = mz % MBP;
    const int zIdx = mz / MBP;

    const int blockM = mIdx * 128;
    const int blockN = nIdx * 256;
    const int kBase = zIdx * KSPLIT;
    const int g = (blockM >= gstart[1]) + (blockM >= gstart[2]) + (blockM >= gstart[3]);
    const int endRow = endv[g];
    const int rootOff = g * 512;

    const int wid = tid >> 6, lane = tid & 63;
    const int wr = wid >> 2, wc = wid & 3;     // 2 x 4 wave grid, 64x64 out each
    const int lr = lane & 15, lg = lane >> 4;

    f32x4 acc[4][4] = {};

    const unsigned short* Abase = A + (size_t)blockM * K_A + kBase;
    const unsigned short* Bbase = WbT + (size_t)blockN * K_B;

    for (int t = 0; t < KSPLIT / BK; ++t) {
        const int k0 = t * BK;
        const int kc = kBase + k0;
        const int bc = (kc < K_MAIN) ? kc : kc + rootOff;   // uniform per 64-tile
#pragma unroll
        for (int q = 0; q < 2; ++q) {
            int c = q * 512 + tid;
            gl16(Abase + (size_t)(c >> 3) * K_A + k0 + (c & 7) * 8, &As[c * 8]);
        }
#pragma unroll
        for (int q = 0; q < 4; ++q) {
            int c = q * 512 + tid;
            gl16(Bbase + (size_t)(c >> 3) * K_B + bc + (c & 7) * 8, &Bs[c * 8]);
        }
        __syncthreads();

#pragma unroll
        for (int ks = 0; ks < 2; ++ks) {
            bf16x8 a_frag[4], b_frag[4];
#pragma unroll
            for (int mi = 0; mi < 4; ++mi) {
                int r = wr * 64 + mi * 16 + lr;
                a_frag[mi] = *reinterpret_cast<const bf16x8*>(
                    &As[r * BK + (((ks * 4 + lg) ^ (r & 7)) << 3)]);
            }
#pragma unroll
            for (int ni = 0; ni < 4; ++ni) {
                int cR = wc * 64 + ni * 16 + lr;
                b_frag[ni] = *reinterpret_cast<const bf16x8*>(
                    &Bs[cR * BK + (((ks * 4 + lg) ^ (cR & 7)) << 3)]);
            }
#pragma unroll
            for (int mi = 0; mi < 4; ++mi)
#pragma unroll
                for (int ni = 0; ni < 4; ++ni)
                    acc[mi][ni] = __builtin_amdgcn_mfma_f32_16x16x32_bf16(
                        a_frag[mi], b_frag[ni], acc[mi][ni], 0, 0, 0);
        }
        __syncthreads();
    }

#pragma unroll
    for (int mi = 0; mi < 4; ++mi) {
#pragma unroll
        for (int r = 0; r < 4; ++r) {
            int row = blockM + wr * 64 + mi * 16 + lg * 4 + r;
            if (row < endRow) {
#pragma unroll
                for (int ni = 0; ni < 4; ++ni) {
                    int col = blockN + wc * 64 + ni * 16 + lr;
                    pbuf[((size_t)zIdx * MPc + row) * D + col] = f2bf(acc[mi][ni][r]);
                }
            }
        }
    }
}

// ---- reduce splits + per-type bias -> f32 out (un-permute rows; NT only on out)
__global__ void reduce_bias(const unsigned short* __restrict__ pbuf,
                            const int* __restrict__ rowperm, const int* __restrict__ tnt,
                            const float* __restrict__ root_b,
                            float* __restrict__ out, int MPc) {
    int idx = blockIdx.x * 256 + threadIdx.x;
    if (idx >= MPc * 64) return;
    int nrow = idx >> 6;
    int col = (idx & 63) * 8;
    int orig = rowperm[nrow];
    if (orig < 0) return;
    float s[8] = {0.f, 0.f, 0.f, 0.f, 0.f, 0.f, 0.f, 0.f};
#pragma unroll
    for (int sp = 0; sp < SPLITS; ++sp) {
        uint4 v = *reinterpret_cast<const uint4*>(pbuf + ((size_t)sp * MPc + nrow) * D + col);
        unsigned u[4] = {v.x, v.y, v.z, v.w};
#pragma unroll
        for (int j = 0; j < 4; ++j) {
            s[2 * j]     += bf2f((unsigned short)(u[j] & 0xFFFF));
            s[2 * j + 1] += bf2f((unsigned short)(u[j] >> 16));
        }
    }
    const float* b = root_b + (size_t)tnt[orig] * D + col;
    float* o = out + (size_t)orig * D + col;
#pragma unroll
    for (int j = 0; j < 8; ++j)
        __builtin_nontemporal_store(s[j] + b[j], o + j);   // out never re-read
}

extern "C" void kernel_launch(void* const* d_in, const int* in_sizes, int n_in,
                              void* d_out, int out_size, void* d_ws, size_t ws_size,
                              hipStream_t stream) {
    const float* x_src    = (const float*)d_in[0];
    const float* x_target = (const float*)d_in[1];
    const float* relW     = (const float*)d_in[2];
    const float* rootW    = (const float*)d_in[3];
    const float* rootb    = (const float*)d_in[4];
    const int*   esrc     = (const int*)d_in[5];
    const int*   edst     = (const int*)d_in[6];
    const int*   etyp     = (const int*)d_in[7];
    const int*   tnt      = (const int*)d_in[8];
    float* out = (float*)d_out;

    const int E = in_sizes[5];
    const int NSRC8 = in_sizes[0] / 8;
    const int M = in_sizes[8];               // n_tgt = 10000
    const int NSEG = M * T_ETYPES;           // 80000
    const int NB = (NSEG + 255) / 256;       // 313
    const int NBT = (M + 255) / 256;         // 40
    const int MBP = (M + 127) / 128 + (NT_TYPES - 1);  // 82
    const int MPc = MBP * 128;               // 10496
    const int segBlocks = (NSEG + 3) / 4;    // 20000
    const int rootBlocks = (M * 64 + 255) / 256;
    const int convBlocks = 2048;
    const int cwBlocks = (K_B / 32) * (D / 32);
    const int histBlocks = (E + 255) / 256;

    char* ws = (char*)d_ws;
    size_t off = 0;
    unsigned short* Abf = (unsigned short*)(ws + off); off += (size_t)MPc * K_A * 2;
    unsigned short* WbT = (unsigned short*)(ws + off); off += (size_t)D * K_B * 2;
    // xsb (51.2 MB) and pbuf (64.5 MB) alias: xsb is dead before the GEMM writes pbuf.
    size_t xsb_bytes = (size_t)in_sizes[0] * 2;
    size_t pb_bytes  = (size_t)SPLITS * MPc * D * 2;
    size_t alias_bytes = pb_bytes > xsb_bytes ? pb_bytes : xsb_bytes;
    unsigned short* xsb = (unsigned short*)(ws + off);
    unsigned short* pb  = (unsigned short*)(ws + off);
    off += alias_bytes;
    int* counts    = (int*)(ws + off); off += (size_t)NSEG * 4;
    int* partial   = (int*)(ws + off); off += (size_t)NSEG * 4;
    int* offsets   = (int*)(ws + off); off += (size_t)(NSEG + 8) * 4;
    int* cursors   = (int*)(ws + off); off += (size_t)NSEG * 4;
    int* blockSums = (int*)(ws + off); off += 512 * 4;
    int* perm      = (int*)(ws + off); off += (size_t)E * 4;
    int* bcnt      = (int*)(ws + off); off += (size_t)NBT * NT_TYPES * 4;
    int* boff      = (int*)(ws + off); off += (size_t)NBT * NT_TYPES * 4;
    int* gstart    = (int*)(ws + off); off += 8 * 4;
    int* endv      = (int*)(ws + off); off += 8 * 4;
    int* rowperm   = (int*)(ws + off); off += (size_t)MPc * 4;
    int* invperm   = (int*)(ws + off); off += (size_t)M * 4;

    hipMemsetAsync(counts, 0, (size_t)NSEG * 4, stream);
    hipMemsetAsync(rowperm, 0xFF, (size_t)MPc * 4, stream);

    // fused front: conv_xsrc || conv_weights || hist || thist2
    front_kernel<<<convBlocks + cwBlocks + histBlocks + NBT, 256, 0, stream>>>(
        x_src, xsb, NSRC8, relW, rootW, WbT, edst, etyp, counts, E,
        tnt, bcnt, M, convBlocks, cwBlocks, histBlocks);
    // fused: scan1 || tprep2
    mid1<<<NB + 1, 256, 0, stream>>>(counts, partial, blockSums, NSEG,
                                     bcnt, NBT, boff, gstart, endv, NB);
    // fused: scan2 || tscatter2
    mid2<<<1 + (NBT + 1) / 2, 512, 0, stream>>>(blockSums, NB, tnt, boff,
                                                rowperm, invperm, M, NBT);
    scan3<<<NB, 256, 0, stream>>>(partial, blockSums, offsets, cursors, NSEG, E);
    scatter_kernel<<<histBlocks, 256, 0, stream>>>(esrc, edst, etyp, cursors, perm, E);
    // build A (bf16 gather + fused rootfill, swizzled)
    build_A<<<segBlocks + rootBlocks, 256, 0, stream>>>(
        xsb, perm, offsets, invperm, x_target, Abf, NSEG, segBlocks, M);
    // GEMM (128x256 tile, 512 threads) + reduce
    rgcn_gemm_sk<<<MBP * 2 * SPLITS, 512, 0, stream>>>(Abf, WbT, pb, gstart, endv, MBP, MPc);
    reduce_bias<<<(MPc * 64 + 255) / 256, 256, 0, stream>>>(pb, rowperm, tnt, rootb, out, MPc);
}